// Round 5
// baseline (88.801 us; speedup 1.0000x reference)
//
#include <hip/hip_runtime.h>

#define BLK   256
#define ROWS  16
#define OWN_PER_BLK (ROWS * BLK)   // 4096
#define CHUNK 200                  // stream points per y-block (multiple of 4, <= BLK)
#define NQ    (CHUNK / 4)

__device__ __forceinline__ float min3f(float a, float b, float c) {
    float d;
    asm("v_min3_f32 %0, %1, %2, %3" : "=v"(d) : "v"(a), "v"(b), "v"(c));
    return d;
}

// Order-preserving float -> uint key: min over keys == min over floats.
__device__ __forceinline__ unsigned int f2key(float f) {
    unsigned int b = __float_as_uint(f);
    return (b & 0x80000000u) ? ~b : (b | 0x80000000u);
}
__device__ __forceinline__ float key2f(unsigned int k) {
    unsigned int b = (k & 0x80000000u) ? (k ^ 0x80000000u) : ~k;
    return __uint_as_float(b);
}

__global__ void chamfer_init(unsigned int* __restrict__ minF, unsigned int* __restrict__ minB,
                             int nP, int nG)
{
    int i = blockIdx.x * blockDim.x + threadIdx.x;
    if (i < nP) minF[i] = 0xFFFFFFFFu;
    if (i < nG) minB[i] = 0xFFFFFFFFu;
}

// Each thread owns ROWS points held in NAMED scalar registers (no arrays ->
// compiler cannot strip-mine / re-read LDS per row group). Block stages CHUNK
// opposite-set points into LDS, transformed to (-2x,-2y,-2z,|s|^2) on the fly.
// Hot loop: 4 uniform ds_read_b128 + ROWS*(12 fma + 2 min3) per quad.
// Tracks min over e = |s|^2 - 2<p,s>; |p|^2 added at finalize (commutes).
__global__ __launch_bounds__(BLK, 4) void chamfer_min(
    const float* __restrict__ pred, const float* __restrict__ gt,
    unsigned int* __restrict__ minF, unsigned int* __restrict__ minB,
    int nP, int nG)
{
    __shared__ float4 sh[CHUNK];

    const int dir = blockIdx.z;                 // 0: own pred / stream gt
    const int nOwn = dir ? nG : nP;
    const int nStr = dir ? nP : nG;
    unsigned int* mins = dir ? minB : minF;

    // --- stage chunk into LDS, transformed; pads get w=3e38 (never win) ---
    {
        const int j = threadIdx.x;
        if (j < CHUNK) {
            const int g = blockIdx.y * CHUNK + j;
            float x = 0.f, y = 0.f, z = 0.f, w = 3.0e38f;
            if (g < nStr) {
                if (dir == 0) { float4 G = ((const float4*)gt)[g]; x = G.x; y = G.y; z = G.z; }
                else          { x = pred[3*g+0]; y = pred[3*g+1]; z = pred[3*g+2]; }
                w = fmaf(x, x, fmaf(y, y, z*z));
                x *= -2.f; y *= -2.f; z *= -2.f;
            }
            sh[j] = make_float4(x, y, z, w);
        }
    }

    const int base = blockIdx.x * OWN_PER_BLK + threadIdx.x;

#define ROW_DECL(k) float Px##k, Py##k, Pz##k, e##k;
    ROW_DECL(0)  ROW_DECL(1)  ROW_DECL(2)  ROW_DECL(3)
    ROW_DECL(4)  ROW_DECL(5)  ROW_DECL(6)  ROW_DECL(7)
    ROW_DECL(8)  ROW_DECL(9)  ROW_DECL(10) ROW_DECL(11)
    ROW_DECL(12) ROW_DECL(13) ROW_DECL(14) ROW_DECL(15)

#define ROW_LOAD(k) { \
        const int r = base + (k) * BLK; \
        const int rc = r < nOwn ? r : (nOwn - 1); \
        if (dir == 0) { Px##k = pred[3*rc+0]; Py##k = pred[3*rc+1]; Pz##k = pred[3*rc+2]; } \
        else          { float4 G = ((const float4*)gt)[rc]; Px##k = G.x; Py##k = G.y; Pz##k = G.z; } \
        e##k = 3.0e38f; }
    ROW_LOAD(0)  ROW_LOAD(1)  ROW_LOAD(2)  ROW_LOAD(3)
    ROW_LOAD(4)  ROW_LOAD(5)  ROW_LOAD(6)  ROW_LOAD(7)
    ROW_LOAD(8)  ROW_LOAD(9)  ROW_LOAD(10) ROW_LOAD(11)
    ROW_LOAD(12) ROW_LOAD(13) ROW_LOAD(14) ROW_LOAD(15)

    __syncthreads();

    #pragma unroll 1
    for (int q = 0; q < NQ; ++q) {
        const float4 s0 = sh[4*q+0], s1 = sh[4*q+1], s2 = sh[4*q+2], s3 = sh[4*q+3];
#define ROW_BODY(k) { \
        float t0 = fmaf(s0.x, Px##k, fmaf(s0.y, Py##k, fmaf(s0.z, Pz##k, s0.w))); \
        float t1 = fmaf(s1.x, Px##k, fmaf(s1.y, Py##k, fmaf(s1.z, Pz##k, s1.w))); \
        float t2 = fmaf(s2.x, Px##k, fmaf(s2.y, Py##k, fmaf(s2.z, Pz##k, s2.w))); \
        float t3 = fmaf(s3.x, Px##k, fmaf(s3.y, Py##k, fmaf(s3.z, Pz##k, s3.w))); \
        e##k = min3f(e##k, t0, t1); \
        e##k = min3f(e##k, t2, t3); }
        ROW_BODY(0)  ROW_BODY(1)  ROW_BODY(2)  ROW_BODY(3)
        ROW_BODY(4)  ROW_BODY(5)  ROW_BODY(6)  ROW_BODY(7)
        ROW_BODY(8)  ROW_BODY(9)  ROW_BODY(10) ROW_BODY(11)
        ROW_BODY(12) ROW_BODY(13) ROW_BODY(14) ROW_BODY(15)
    }

#define ROW_STORE(k) { \
        const int r = base + (k) * BLK; \
        if (r < nOwn) atomicMin(&mins[r], f2key(e##k)); }
    ROW_STORE(0)  ROW_STORE(1)  ROW_STORE(2)  ROW_STORE(3)
    ROW_STORE(4)  ROW_STORE(5)  ROW_STORE(6)  ROW_STORE(7)
    ROW_STORE(8)  ROW_STORE(9)  ROW_STORE(10) ROW_STORE(11)
    ROW_STORE(12) ROW_STORE(13) ROW_STORE(14) ROW_STORE(15)
}

// Single block: decode keys, add |p|^2 (recomputed from raw inputs), clamp, mean.
__global__ __launch_bounds__(1024) void chamfer_finalize(
    const unsigned int* __restrict__ minF, const unsigned int* __restrict__ minB,
    const float* __restrict__ pred, const float* __restrict__ gt,
    float* __restrict__ out, int nP, int nG)
{
    float sF = 0.f, sB = 0.f;
    const int nmax = nP > nG ? nP : nG;
    for (int i = threadIdx.x; i < nmax; i += blockDim.x) {
        if (i < nP) {
            float px = pred[3*i+0], py = pred[3*i+1], pz = pred[3*i+2];
            float p2 = fmaf(px, px, fmaf(py, py, pz*pz));
            sF += fmaxf(0.f, p2 + key2f(minF[i]));
        }
        if (i < nG) {
            float4 G = ((const float4*)gt)[i];
            float g2 = fmaf(G.x, G.x, fmaf(G.y, G.y, G.z*G.z));
            sB += fmaxf(0.f, g2 + key2f(minB[i]));
        }
    }
    #pragma unroll
    for (int o = 32; o > 0; o >>= 1) { sF += __shfl_xor(sF, o); sB += __shfl_xor(sB, o); }
    __shared__ float rF[16], rB[16];
    const int wid = threadIdx.x >> 6, lane = threadIdx.x & 63;
    if (lane == 0) { rF[wid] = sF; rB[wid] = sB; }
    __syncthreads();
    if (threadIdx.x == 0) {
        float tF = 0.f, tB = 0.f;
        const int nw = (int)(blockDim.x >> 6);
        for (int w = 0; w < nw; ++w) { tF += rF[w]; tB += rB[w]; }
        out[0] = tF / (float)nP + tB / (float)nG;
    }
}

extern "C" void kernel_launch(void* const* d_in, const int* in_sizes, int n_in,
                              void* d_out, int out_size, void* d_ws, size_t ws_size,
                              hipStream_t stream)
{
    const float* pred = (const float*)d_in[0];
    const float* gt   = (const float*)d_in[1];
    const int nP = in_sizes[0] / 3;
    const int nG = in_sizes[1] / 4;

    unsigned int* minF = (unsigned int*)d_ws;
    unsigned int* minB = minF + ((nP + 63) & ~63);
    (void)ws_size; (void)n_in; (void)out_size;

    const int nmax = nP > nG ? nP : nG;
    chamfer_init<<<(nmax + 255) / 256, 256, 0, stream>>>(minF, minB, nP, nG);

    const int xB = (nmax + OWN_PER_BLK - 1) / OWN_PER_BLK;   // 5
    const int yB = (nmax + CHUNK - 1) / CHUNK;               // 100
    dim3 grid(xB, yB, 2);
    chamfer_min<<<grid, BLK, 0, stream>>>(pred, gt, minF, minB, nP, nG);

    chamfer_finalize<<<1, 1024, 0, stream>>>(minF, minB, pred, gt, (float*)d_out, nP, nG);
}

// Round 7
// 66.482 us; speedup vs baseline: 1.3357x; 1.3357x over previous
//
#include <hip/hip_runtime.h>

typedef __bf16 bf16x8 __attribute__((ext_vector_type(8)));
typedef float f32x16 __attribute__((ext_vector_type(16)));

#define BLK      256
#define WAVES    4
#define SPLIT    16     // stream-dimension grid split
#define CH_TILES 40     // stream tiles per LDS chunk: 40*64*16B = 40 KB

__device__ __forceinline__ float min3f(float a, float b, float c) {
    float d;
    asm("v_min3_f32 %0, %1, %2, %3" : "=v"(d) : "v"(a), "v"(b), "v"(c));
    return d;
}
// Order-preserving float -> uint key: min over keys == min over floats.
__device__ __forceinline__ unsigned int f2key(float f) {
    unsigned int b = __float_as_uint(f);
    return (b & 0x80000000u) ? ~b : (b | 0x80000000u);
}
__device__ __forceinline__ float key2f(unsigned int k) {
    unsigned int b = (k & 0x80000000u) ? (k ^ 0x80000000u) : ~k;
    return __uint_as_float(b);
}

// 16B split record per point: {xh,xl,yh,yl,zh,zl,s2h,s2l} (hi/lo bf16 splits).
// Pad slots get {0,...,0,big,big} -> d2 contribution 2e30 (never wins a min).
// Also inits the min-key arrays.
__global__ void expandSplit(const float* __restrict__ pred, const float* __restrict__ gt,
                            bf16x8* __restrict__ predS, bf16x8* __restrict__ gtS,
                            unsigned int* __restrict__ minF, unsigned int* __restrict__ minB,
                            int nP, int nG, int slotsP, int slotsG)
{
    const int i = blockIdx.x * blockDim.x + threadIdx.x;
    const __bf16 zero = (__bf16)0.0f, big = (__bf16)1.0e30f;
    if (i < slotsP) {
        bf16x8 h = {zero, zero, zero, zero, zero, zero, big, big};
        if (i < nP) {
            float x = pred[3*i], y = pred[3*i+1], z = pred[3*i+2];
            float s2 = fmaf(x, x, fmaf(y, y, z*z));
            __bf16 xh = (__bf16)x, yh = (__bf16)y, zh = (__bf16)z;
            __bf16 xl = (__bf16)(x - (float)xh), yl = (__bf16)(y - (float)yh), zl = (__bf16)(z - (float)zh);
            __bf16 s2h = (__bf16)s2, s2l = (__bf16)(s2 - (float)s2h);
            h = bf16x8{xh, xl, yh, yl, zh, zl, s2h, s2l};
            minF[i] = 0xFFFFFFFFu;
        }
        predS[i] = h;
    }
    if (i < slotsG) {
        bf16x8 h = {zero, zero, zero, zero, zero, zero, big, big};
        if (i < nG) {
            float4 G = ((const float4*)gt)[i];
            float x = G.x, y = G.y, z = G.z;
            float s2 = fmaf(x, x, fmaf(y, y, z*z));
            __bf16 xh = (__bf16)x, yh = (__bf16)y, zh = (__bf16)z;
            __bf16 xl = (__bf16)(x - (float)xh), yl = (__bf16)(y - (float)yh), zl = (__bf16)(z - (float)zh);
            __bf16 s2h = (__bf16)s2, s2l = (__bf16)(s2 - (float)s2h);
            h = bf16x8{xh, xl, yh, yl, zh, zl, s2h, s2l};
            minB[i] = 0xFFFFFFFFu;
        }
        gtS[i] = h;
    }
}

// d2 = p2 + g2 - 2<p,g> via one mfma_f32_32x32x16_bf16 per (own,stream) tile
// pair. K recipe (A=stream row | B=own col):
//   k0:1|p2h k1:1|p2l k2:g2h|1 k3:g2l|1
//   x: k4:gxh|-2pxh k5:gxl|-2pxh k6:gxh|-2pxl   (y: k7-9, z: k10-12; k13-15: 0)
// Exact to ~2^-17 (dropped l*l terms). Any k-permutation of the HW fragment
// layout cancels (A and B share the same lane->k map); C/D col=lane&31 is
// HW-verified; row attribution is irrelevant (min over all 16 regs + both
// lane halves atomicMin the same own index).
__global__ __launch_bounds__(BLK) void chamfer_mfma(
    const bf16x8* __restrict__ predS, const bf16x8* __restrict__ gtS,
    unsigned int* __restrict__ minF, unsigned int* __restrict__ minB,
    int nP, int nG)
{
    __shared__ bf16x8 sh[CH_TILES * 64];

    const int dir  = blockIdx.z;            // 0: own pred / stream gt
    const int nOwn = dir ? nG : nP;
    const int nStr = dir ? nP : nG;
    const int ownTiles = (nOwn + 31) >> 5;
    const int strTiles = (nStr + 31) >> 5;
    const bf16x8* __restrict__ strS = dir ? predS : gtS;
    const bf16x8* __restrict__ ownS = dir ? gtS : predS;
    unsigned int* mins = dir ? minB : minF;

    const int tid = threadIdx.x, wave = tid >> 6, lane = tid & 63, col = lane & 31;
    const int myTile = blockIdx.x * WAVES + wave;
    const bool tValid = myTile < ownTiles;
    const int idx = myTile * 32 + col;

    const __bf16 one = (__bf16)1.0f, zero = (__bf16)0.0f;

    // ---- B fragment for own point at col (x(-2) on bf16 is exact) ----
    {
    }
    bf16x8 s = ownS[min(idx, nOwn - 1)];
    const __bf16 m2xh = (__bf16)(-2.0f*(float)s[0]), m2xl = (__bf16)(-2.0f*(float)s[1]);
    const __bf16 m2yh = (__bf16)(-2.0f*(float)s[2]), m2yl = (__bf16)(-2.0f*(float)s[3]);
    const __bf16 m2zh = (__bf16)(-2.0f*(float)s[4]), m2zl = (__bf16)(-2.0f*(float)s[5]);
    const bf16x8 bfrag = (lane < 32)
        ? bf16x8{s[6], s[7], one, one, m2xh, m2xh, m2xl, m2yh}
        : bf16x8{m2yh, m2yl, m2zh, m2zh, m2zl, zero, zero, zero};

    float rm[8];
    #pragma unroll
    for (int j = 0; j < 8; ++j) rm[j] = 3.0e38f;
    const f32x16 zc = {};

    const int perY = (strTiles + SPLIT - 1) / SPLIT;
    const int t0 = blockIdx.y * perY;
    const int t1 = min(t0 + perY, strTiles);

    for (int cs = t0; cs < t1; cs += CH_TILES) {
        const int cnt = min(CH_TILES, t1 - cs);
        __syncthreads();                         // protect previous chunk readers
        for (int j = tid; j < cnt * 32; j += BLK) {
            bf16x8 r = strS[cs * 32 + j];        // < strTiles*32 slots: valid
            const int t = j >> 5, q = j & 31;
            sh[t*64 + q]      = bf16x8{one, one, r[6], r[7], r[0], r[1], r[0], r[2]};
            sh[t*64 + 32 + q] = bf16x8{r[3], r[2], r[4], r[5], r[4], zero, zero, zero};
        }
        __syncthreads();
        for (int t = 0; t < cnt; ++t) {
            bf16x8 af = sh[t * 64 + lane];
            f32x16 d = __builtin_amdgcn_mfma_f32_32x32x16_bf16(af, bfrag, zc, 0, 0, 0);
            #pragma unroll
            for (int j = 0; j < 8; ++j)
                rm[j] = min3f(d[2*j], d[2*j+1], rm[j]);
        }
    }

    const float a = min3f(rm[0], rm[1], rm[2]);
    const float b = min3f(rm[3], rm[4], rm[5]);
    const float c = min3f(rm[6], rm[7], a);
    const float m = fminf(fminf(b, c), 3.0e38f);   // also NaN-sanitizes
    if (tValid && idx < nOwn) atomicMin(&mins[idx], f2key(m));
}

// Decode keys (full d2), clamp, mean both directions. Untouched keys decode
// to 1e30 so a non-running min kernel shows as a HUGE error, not 0.
__global__ __launch_bounds__(1024) void chamfer_finalize(
    const unsigned int* __restrict__ minF, const unsigned int* __restrict__ minB,
    float* __restrict__ out, int nP, int nG)
{
    float sF = 0.f, sB = 0.f;
    const int nmax = nP > nG ? nP : nG;
    for (int i = threadIdx.x; i < nmax; i += blockDim.x) {
        if (i < nP) {
            unsigned int k = minF[i];
            float v = (k == 0xFFFFFFFFu) ? 1.0e30f : key2f(k);
            sF += fmaxf(0.f, v);
        }
        if (i < nG) {
            unsigned int k = minB[i];
            float v = (k == 0xFFFFFFFFu) ? 1.0e30f : key2f(k);
            sB += fmaxf(0.f, v);
        }
    }
    #pragma unroll
    for (int o = 32; o > 0; o >>= 1) { sF += __shfl_xor(sF, o); sB += __shfl_xor(sB, o); }
    __shared__ float rF[16], rB[16];
    const int wid = threadIdx.x >> 6, lane = threadIdx.x & 63;
    if (lane == 0) { rF[wid] = sF; rB[wid] = sB; }
    __syncthreads();
    if (threadIdx.x == 0) {
        float tF = 0.f, tB = 0.f;
        const int nw = (int)(blockDim.x >> 6);
        for (int w = 0; w < nw; ++w) { tF += rF[w]; tB += rB[w]; }
        out[0] = tF / (float)nP + tB / (float)nG;
    }
}

extern "C" void kernel_launch(void* const* d_in, const int* in_sizes, int n_in,
                              void* d_out, int out_size, void* d_ws, size_t ws_size,
                              hipStream_t stream)
{
    const float* pred = (const float*)d_in[0];
    const float* gt   = (const float*)d_in[1];
    const int nP = in_sizes[0] / 3;
    const int nG = in_sizes[1] / 4;
    const int tilesP = (nP + 31) / 32, tilesG = (nG + 31) / 32;
    const int slotsP = tilesP * 32, slotsG = tilesG * 32;

    char* ws = (char*)d_ws;
    size_t off = 0;
    auto take = [&](size_t bytes) -> void* {
        void* p = ws + off;
        off = (off + bytes + 255) & ~(size_t)255;
        return p;
    };
    // 16B/point records: same 800 KB footprint as the passing scalar rounds.
    bf16x8* predS = (bf16x8*)take((size_t)slotsP * 16);
    bf16x8* gtS   = (bf16x8*)take((size_t)slotsG * 16);
    unsigned int* minF = (unsigned int*)take((size_t)nP * 4);
    unsigned int* minB = (unsigned int*)take((size_t)nG * 4);
    (void)ws_size; (void)n_in; (void)out_size;

    const int smax = slotsP > slotsG ? slotsP : slotsG;
    expandSplit<<<(smax + 255) / 256, 256, 0, stream>>>(pred, gt, predS, gtS, minF, minB,
                                                        nP, nG, slotsP, slotsG);

    const int maxTiles = tilesP > tilesG ? tilesP : tilesG;
    dim3 grid((maxTiles + WAVES - 1) / WAVES, SPLIT, 2);
    chamfer_mfma<<<grid, BLK, 0, stream>>>(predS, gtS, minF, minB, nP, nG);

    chamfer_finalize<<<1, 1024, 0, stream>>>(minF, minB, (float*)d_out, nP, nG);
}

// Round 8
// 63.246 us; speedup vs baseline: 1.4041x; 1.0512x over previous
//
#include <hip/hip_runtime.h>

typedef __bf16 bf16x8 __attribute__((ext_vector_type(8)));
typedef float f32x16 __attribute__((ext_vector_type(16)));

#define BLK      256
#define WAVES    4
#define SPLIT    16                      // stream-dimension grid split
#define CH_TILES 40                      // tiles per block: 40*64*16B = 40 KB LDS
#define PAD_TILES (SPLIT * CH_TILES)     // 640 stream tiles after padding
#define PAD_SLOTS (PAD_TILES * 32)       // 20480 point slots

__device__ __forceinline__ float min3f(float a, float b, float c) {
    float d;
    asm("v_min3_f32 %0, %1, %2, %3" : "=v"(d) : "v"(a), "v"(b), "v"(c));
    return d;
}
// Order-preserving float -> uint key: min over keys == min over floats.
__device__ __forceinline__ unsigned int f2key(float f) {
    unsigned int b = __float_as_uint(f);
    return (b & 0x80000000u) ? ~b : (b | 0x80000000u);
}
__device__ __forceinline__ float key2f(unsigned int k) {
    unsigned int b = (k & 0x80000000u) ? (k ^ 0x80000000u) : ~k;
    return __uint_as_float(b);
}

// 16B split record per point: {xh,xl,yh,yl,zh,zl,s2h,s2l}. Pad slots get
// {0,...,0,big,big} -> d2 contribution 2e30 (never wins a min). Both arrays
// are padded to PAD_SLOTS so the min kernel has no bounds logic at all.
__global__ void expandSplit(const float* __restrict__ pred, const float* __restrict__ gt,
                            bf16x8* __restrict__ predS, bf16x8* __restrict__ gtS,
                            unsigned int* __restrict__ minF, unsigned int* __restrict__ minB,
                            int nP, int nG)
{
    const int i = blockIdx.x * blockDim.x + threadIdx.x;
    if (i >= PAD_SLOTS) return;
    const __bf16 zero = (__bf16)0.0f, big = (__bf16)1.0e30f;
    {
        bf16x8 h = {zero, zero, zero, zero, zero, zero, big, big};
        if (i < nP) {
            float x = pred[3*i], y = pred[3*i+1], z = pred[3*i+2];
            float s2 = fmaf(x, x, fmaf(y, y, z*z));
            __bf16 xh = (__bf16)x, yh = (__bf16)y, zh = (__bf16)z;
            __bf16 xl = (__bf16)(x - (float)xh), yl = (__bf16)(y - (float)yh), zl = (__bf16)(z - (float)zh);
            __bf16 s2h = (__bf16)s2, s2l = (__bf16)(s2 - (float)s2h);
            h = bf16x8{xh, xl, yh, yl, zh, zl, s2h, s2l};
            minF[i] = 0xFFFFFFFFu;
        }
        predS[i] = h;
    }
    {
        bf16x8 h = {zero, zero, zero, zero, zero, zero, big, big};
        if (i < nG) {
            float4 G = ((const float4*)gt)[i];
            float x = G.x, y = G.y, z = G.z;
            float s2 = fmaf(x, x, fmaf(y, y, z*z));
            __bf16 xh = (__bf16)x, yh = (__bf16)y, zh = (__bf16)z;
            __bf16 xl = (__bf16)(x - (float)xh), yl = (__bf16)(y - (float)yh), zl = (__bf16)(z - (float)zh);
            __bf16 s2h = (__bf16)s2, s2l = (__bf16)(s2 - (float)s2h);
            h = bf16x8{xh, xl, yh, yl, zh, zl, s2h, s2l};
            minB[i] = 0xFFFFFFFFu;
        }
        gtS[i] = h;
    }
}

// d2 = p2 + g2 - 2<p,g> via one mfma_f32_32x32x16_bf16 per (own,stream) tile
// pair. K recipe (A=stream row | B=own col):
//   k0:1|p2h k1:1|p2l k2:g2h|1 k3:g2l|1
//   x: k4:gxh|-2pxh k5:gxl|-2pxh k6:gxh|-2pxl  (y: k7-9, z: k10-12; k13-15: 0)
// Exact to ~2^-17 (verified absmax 0.0 in round 7). Each block: stage exactly
// CH_TILES stream tiles (A-layout) into LDS, one sync, then a fully-unrolled
// loop of {ds_read_b128 (imm offset) + MFMA + 8 v_min3}. MFMA-pipe floor:
// 785 tiles/SIMD * 32 cyc = ~10.5 us.
__global__ __launch_bounds__(BLK) void chamfer_mfma(
    const bf16x8* __restrict__ predS, const bf16x8* __restrict__ gtS,
    unsigned int* __restrict__ minF, unsigned int* __restrict__ minB,
    int nP, int nG)
{
    __shared__ bf16x8 sh[CH_TILES * 64];

    const int dir  = blockIdx.z;            // 0: own pred / stream gt
    const int nOwn = dir ? nG : nP;
    const int ownTiles = (nOwn + 31) >> 5;
    const bf16x8* __restrict__ strS = dir ? predS : gtS;
    const bf16x8* __restrict__ ownS = dir ? gtS : predS;
    unsigned int* mins = dir ? minB : minF;

    const int tid = threadIdx.x, wave = tid >> 6, lane = tid & 63, col = lane & 31;
    const int myTile = blockIdx.x * WAVES + wave;
    const bool tValid = myTile < ownTiles;
    const int idx = myTile * 32 + col;

    const __bf16 one = (__bf16)1.0f, zero = (__bf16)0.0f;

    // ---- B fragment for own point at col (x(-2) on bf16 is exact) ----
    bf16x8 s = ownS[min(idx, nOwn - 1)];
    const __bf16 m2xh = (__bf16)(-2.0f*(float)s[0]), m2xl = (__bf16)(-2.0f*(float)s[1]);
    const __bf16 m2yh = (__bf16)(-2.0f*(float)s[2]), m2yl = (__bf16)(-2.0f*(float)s[3]);
    const __bf16 m2zh = (__bf16)(-2.0f*(float)s[4]), m2zl = (__bf16)(-2.0f*(float)s[5]);
    const bf16x8 bfrag = (lane < 32)
        ? bf16x8{s[6], s[7], one, one, m2xh, m2xh, m2xl, m2yh}
        : bf16x8{m2yh, m2yl, m2zh, m2zh, m2zl, zero, zero, zero};

    // ---- stage CH_TILES stream tiles into LDS in A-layout ----
    #pragma unroll
    for (int j = tid; j < CH_TILES * 32; j += BLK) {
        bf16x8 r = strS[blockIdx.y * (CH_TILES * 32) + j];   // padded: always valid
        const int t = j >> 5, q = j & 31;
        sh[t*64 + q]      = bf16x8{one, one, r[6], r[7], r[0], r[1], r[0], r[2]};
        sh[t*64 + 32 + q] = bf16x8{r[3], r[2], r[4], r[5], r[4], zero, zero, zero};
    }
    __syncthreads();

    float rm[8];
    #pragma unroll
    for (int j = 0; j < 8; ++j) rm[j] = 3.0e38f;
    const f32x16 zc = {};

    #pragma unroll
    for (int t = 0; t < CH_TILES; ++t) {
        bf16x8 af = sh[t * 64 + lane];
        f32x16 d = __builtin_amdgcn_mfma_f32_32x32x16_bf16(af, bfrag, zc, 0, 0, 0);
        #pragma unroll
        for (int j = 0; j < 8; ++j)
            rm[j] = min3f(d[2*j], d[2*j+1], rm[j]);
    }

    const float a = min3f(rm[0], rm[1], rm[2]);
    const float b = min3f(rm[3], rm[4], rm[5]);
    const float c = min3f(rm[6], rm[7], a);
    const float m = fminf(fminf(b, c), 3.0e38f);   // also NaN-sanitizes
    if (tValid && idx < nOwn) atomicMin(&mins[idx], f2key(m));
}

// Decode keys (full d2), clamp, mean both directions. Untouched keys decode
// to 1e30 so a non-running min kernel shows as a HUGE error, not 0.
__global__ __launch_bounds__(1024) void chamfer_finalize(
    const unsigned int* __restrict__ minF, const unsigned int* __restrict__ minB,
    float* __restrict__ out, int nP, int nG)
{
    float sF = 0.f, sB = 0.f;
    const int nmax = nP > nG ? nP : nG;
    for (int i = threadIdx.x; i < nmax; i += blockDim.x) {
        if (i < nP) {
            unsigned int k = minF[i];
            sF += fmaxf(0.f, (k == 0xFFFFFFFFu) ? 1.0e30f : key2f(k));
        }
        if (i < nG) {
            unsigned int k = minB[i];
            sB += fmaxf(0.f, (k == 0xFFFFFFFFu) ? 1.0e30f : key2f(k));
        }
    }
    #pragma unroll
    for (int o = 32; o > 0; o >>= 1) { sF += __shfl_xor(sF, o); sB += __shfl_xor(sB, o); }
    __shared__ float rF[16], rB[16];
    const int wid = threadIdx.x >> 6, lane = threadIdx.x & 63;
    if (lane == 0) { rF[wid] = sF; rB[wid] = sB; }
    __syncthreads();
    if (threadIdx.x == 0) {
        float tF = 0.f, tB = 0.f;
        const int nw = (int)(blockDim.x >> 6);
        for (int w = 0; w < nw; ++w) { tF += rF[w]; tB += rB[w]; }
        out[0] = tF / (float)nP + tB / (float)nG;
    }
}

extern "C" void kernel_launch(void* const* d_in, const int* in_sizes, int n_in,
                              void* d_out, int out_size, void* d_ws, size_t ws_size,
                              hipStream_t stream)
{
    const float* pred = (const float*)d_in[0];
    const float* gt   = (const float*)d_in[1];
    const int nP = in_sizes[0] / 3;
    const int nG = in_sizes[1] / 4;
    const int tilesP = (nP + 31) / 32, tilesG = (nG + 31) / 32;

    char* ws = (char*)d_ws;
    size_t off = 0;
    auto take = [&](size_t bytes) -> void* {
        void* p = ws + off;
        off = (off + bytes + 255) & ~(size_t)255;
        return p;
    };
    // ~815 KB total: proven-safe footprint.
    bf16x8* predS = (bf16x8*)take((size_t)PAD_SLOTS * 16);
    bf16x8* gtS   = (bf16x8*)take((size_t)PAD_SLOTS * 16);
    unsigned int* minF = (unsigned int*)take((size_t)nP * 4);
    unsigned int* minB = (unsigned int*)take((size_t)nG * 4);
    (void)ws_size; (void)n_in; (void)out_size;

    expandSplit<<<(PAD_SLOTS + 255) / 256, 256, 0, stream>>>(pred, gt, predS, gtS,
                                                             minF, minB, nP, nG);

    const int maxTiles = tilesP > tilesG ? tilesP : tilesG;
    dim3 grid((maxTiles + WAVES - 1) / WAVES, SPLIT, 2);
    chamfer_mfma<<<grid, BLK, 0, stream>>>(predS, gtS, minF, minB, nP, nG);

    chamfer_finalize<<<1, 1024, 0, stream>>>(minF, minB, (float*)d_out, nP, nG);
}

// Round 9
// 54.237 us; speedup vs baseline: 1.6373x; 1.1661x over previous
//
#include <hip/hip_runtime.h>

typedef __bf16 bf16x8 __attribute__((ext_vector_type(8)));
typedef float f32x16 __attribute__((ext_vector_type(16)));

#define BLK      256
#define WAVES    4
#define SPLIT    16                      // stream-dimension grid split
#define CH_TILES 40                      // tiles per block: 40*64*16B = 40 KB LDS
#define PAD_TILES (SPLIT * CH_TILES)     // 640 stream tiles after padding
#define PAD_SLOTS (PAD_TILES * 32)       // 20480 point slots

__device__ __forceinline__ float min3f(float a, float b, float c) {
    float d;
    asm("v_min3_f32 %0, %1, %2, %3" : "=v"(d) : "v"(a), "v"(b), "v"(c));
    return d;
}
// MFMA with explicit separate destination: early-clobber D (=&v) guarantees
// D != {A,B,C}, so the zero-C tuple stays pinned (written ONCE, never
// re-materialized) and D needs no per-iteration init/copies.
__device__ __forceinline__ f32x16 mfma_tile(bf16x8 a, bf16x8 b, f32x16 zc) {
    f32x16 d;
    asm("v_mfma_f32_32x32x16_bf16 %0, %1, %2, %3"
        : "=&v"(d) : "v"(a), "v"(b), "v"(zc));
    return d;
}
// Order-preserving float -> uint key: min over keys == min over floats.
__device__ __forceinline__ unsigned int f2key(float f) {
    unsigned int b = __float_as_uint(f);
    return (b & 0x80000000u) ? ~b : (b | 0x80000000u);
}
__device__ __forceinline__ float key2f(unsigned int k) {
    unsigned int b = (k & 0x80000000u) ? (k ^ 0x80000000u) : ~k;
    return __uint_as_float(b);
}

// 16B split record per point: {xh,xl,yh,yl,zh,zl,s2h,s2l}. Pad slots get
// {0,...,0,big,big} -> d2 contribution 2e30 (never wins a min). Both arrays
// are padded to PAD_SLOTS so the min kernel has no bounds logic at all.
__global__ void expandSplit(const float* __restrict__ pred, const float* __restrict__ gt,
                            bf16x8* __restrict__ predS, bf16x8* __restrict__ gtS,
                            unsigned int* __restrict__ minF, unsigned int* __restrict__ minB,
                            int nP, int nG)
{
    const int i = blockIdx.x * blockDim.x + threadIdx.x;
    if (i >= PAD_SLOTS) return;
    const __bf16 zero = (__bf16)0.0f, big = (__bf16)1.0e30f;
    {
        bf16x8 h = {zero, zero, zero, zero, zero, zero, big, big};
        if (i < nP) {
            float x = pred[3*i], y = pred[3*i+1], z = pred[3*i+2];
            float s2 = fmaf(x, x, fmaf(y, y, z*z));
            __bf16 xh = (__bf16)x, yh = (__bf16)y, zh = (__bf16)z;
            __bf16 xl = (__bf16)(x - (float)xh), yl = (__bf16)(y - (float)yh), zl = (__bf16)(z - (float)zh);
            __bf16 s2h = (__bf16)s2, s2l = (__bf16)(s2 - (float)s2h);
            h = bf16x8{xh, xl, yh, yl, zh, zl, s2h, s2l};
            minF[i] = 0xFFFFFFFFu;
        }
        predS[i] = h;
    }
    {
        bf16x8 h = {zero, zero, zero, zero, zero, zero, big, big};
        if (i < nG) {
            float4 G = ((const float4*)gt)[i];
            float x = G.x, y = G.y, z = G.z;
            float s2 = fmaf(x, x, fmaf(y, y, z*z));
            __bf16 xh = (__bf16)x, yh = (__bf16)y, zh = (__bf16)z;
            __bf16 xl = (__bf16)(x - (float)xh), yl = (__bf16)(y - (float)yh), zl = (__bf16)(z - (float)zh);
            __bf16 s2h = (__bf16)s2, s2l = (__bf16)(s2 - (float)s2h);
            h = bf16x8{xh, xl, yh, yl, zh, zl, s2h, s2l};
            minB[i] = 0xFFFFFFFFu;
        }
        gtS[i] = h;
    }
}

// d2 = p2 + g2 - 2<p,g> via one mfma_f32_32x32x16_bf16 per (own,stream) tile
// pair. K recipe (A=stream row | B=own col):
//   k0:1|p2h k1:1|p2l k2:g2h|1 k3:g2l|1
//   x: k4:gxh|-2pxh k5:gxl|-2pxh k6:gxh|-2pxl  (y: k7-9, z: k10-12; k13-15: 0)
// Exact to ~2^-17 (verified absmax 0.0 in rounds 7/8). Per tile:
// {ds_read_b128 + asm MFMA (pinned zero-C) + 8 v_min3}, ping-ponged 2-deep so
// tile t's fold runs after tile t+1's MFMA issue (also covers the MFMA->VALU
// read hazard window). MFMA-pipe floor: 785 tiles/SIMD * 34 cyc = ~11 us.
__global__ __launch_bounds__(BLK) void chamfer_mfma(
    const bf16x8* __restrict__ predS, const bf16x8* __restrict__ gtS,
    unsigned int* __restrict__ minF, unsigned int* __restrict__ minB,
    int nP, int nG)
{
    __shared__ bf16x8 sh[CH_TILES * 64];

    const int dir  = blockIdx.z;            // 0: own pred / stream gt
    const int nOwn = dir ? nG : nP;
    const int ownTiles = (nOwn + 31) >> 5;
    const bf16x8* __restrict__ strS = dir ? predS : gtS;
    const bf16x8* __restrict__ ownS = dir ? gtS : predS;
    unsigned int* mins = dir ? minB : minF;

    const int tid = threadIdx.x, wave = tid >> 6, lane = tid & 63, col = lane & 31;
    const int myTile = blockIdx.x * WAVES + wave;
    const bool tValid = myTile < ownTiles;
    const int idx = myTile * 32 + col;

    const __bf16 one = (__bf16)1.0f, zero = (__bf16)0.0f;

    // ---- B fragment for own point at col (x(-2) on bf16 is exact) ----
    bf16x8 s = ownS[min(idx, nOwn - 1)];
    const __bf16 m2xh = (__bf16)(-2.0f*(float)s[0]), m2xl = (__bf16)(-2.0f*(float)s[1]);
    const __bf16 m2yh = (__bf16)(-2.0f*(float)s[2]), m2yl = (__bf16)(-2.0f*(float)s[3]);
    const __bf16 m2zh = (__bf16)(-2.0f*(float)s[4]), m2zl = (__bf16)(-2.0f*(float)s[5]);
    const bf16x8 bfrag = (lane < 32)
        ? bf16x8{s[6], s[7], one, one, m2xh, m2xh, m2xl, m2yh}
        : bf16x8{m2yh, m2yl, m2zh, m2zh, m2zl, zero, zero, zero};

    // ---- stage CH_TILES stream tiles into LDS in A-layout ----
    #pragma unroll
    for (int j = tid; j < CH_TILES * 32; j += BLK) {
        bf16x8 r = strS[blockIdx.y * (CH_TILES * 32) + j];   // padded: always valid
        const int t = j >> 5, q = j & 31;
        sh[t*64 + q]      = bf16x8{one, one, r[6], r[7], r[0], r[1], r[0], r[2]};
        sh[t*64 + 32 + q] = bf16x8{r[3], r[2], r[4], r[5], r[4], zero, zero, zero};
    }
    __syncthreads();

    float rm[8];
    #pragma unroll
    for (int j = 0; j < 8; ++j) rm[j] = 3.0e38f;
    f32x16 zc = {};    // pinned zero-C: written once, never re-materialized

#define FOLD(dv) { \
        rm[0] = min3f(dv[0],  dv[1],  rm[0]); \
        rm[1] = min3f(dv[2],  dv[3],  rm[1]); \
        rm[2] = min3f(dv[4],  dv[5],  rm[2]); \
        rm[3] = min3f(dv[6],  dv[7],  rm[3]); \
        rm[4] = min3f(dv[8],  dv[9],  rm[4]); \
        rm[5] = min3f(dv[10], dv[11], rm[5]); \
        rm[6] = min3f(dv[12], dv[13], rm[6]); \
        rm[7] = min3f(dv[14], dv[15], rm[7]); }

    f32x16 dA = mfma_tile(sh[lane], bfrag, zc);
    #pragma unroll
    for (int t = 1; t < CH_TILES; ++t) {
        f32x16 dB = mfma_tile(sh[t * 64 + lane], bfrag, zc);  // issue next first
        FOLD(dA);                                             // fold previous
        dA = dB;
    }
    FOLD(dA);
#undef FOLD

    const float a = min3f(rm[0], rm[1], rm[2]);
    const float b = min3f(rm[3], rm[4], rm[5]);
    const float c = min3f(rm[6], rm[7], a);
    const float m = fminf(fminf(b, c), 3.0e38f);   // also NaN-sanitizes
    if (tValid && idx < nOwn) atomicMin(&mins[idx], f2key(m));
}

// Decode keys (full d2), clamp, mean both directions. Untouched keys decode
// to 1e30 so a non-running min kernel shows as a HUGE error, not 0.
__global__ __launch_bounds__(1024) void chamfer_finalize(
    const unsigned int* __restrict__ minF, const unsigned int* __restrict__ minB,
    float* __restrict__ out, int nP, int nG)
{
    float sF = 0.f, sB = 0.f;
    const int nmax = nP > nG ? nP : nG;
    for (int i = threadIdx.x; i < nmax; i += blockDim.x) {
        if (i < nP) {
            unsigned int k = minF[i];
            sF += fmaxf(0.f, (k == 0xFFFFFFFFu) ? 1.0e30f : key2f(k));
        }
        if (i < nG) {
            unsigned int k = minB[i];
            sB += fmaxf(0.f, (k == 0xFFFFFFFFu) ? 1.0e30f : key2f(k));
        }
    }
    #pragma unroll
    for (int o = 32; o > 0; o >>= 1) { sF += __shfl_xor(sF, o); sB += __shfl_xor(sB, o); }
    __shared__ float rF[16], rB[16];
    const int wid = threadIdx.x >> 6, lane = threadIdx.x & 63;
    if (lane == 0) { rF[wid] = sF; rB[wid] = sB; }
    __syncthreads();
    if (threadIdx.x == 0) {
        float tF = 0.f, tB = 0.f;
        const int nw = (int)(blockDim.x >> 6);
        for (int w = 0; w < nw; ++w) { tF += rF[w]; tB += rB[w]; }
        out[0] = tF / (float)nP + tB / (float)nG;
    }
}

extern "C" void kernel_launch(void* const* d_in, const int* in_sizes, int n_in,
                              void* d_out, int out_size, void* d_ws, size_t ws_size,
                              hipStream_t stream)
{
    const float* pred = (const float*)d_in[0];
    const float* gt   = (const float*)d_in[1];
    const int nP = in_sizes[0] / 3;
    const int nG = in_sizes[1] / 4;
    const int tilesP = (nP + 31) / 32, tilesG = (nG + 31) / 32;

    char* ws = (char*)d_ws;
    size_t off = 0;
    auto take = [&](size_t bytes) -> void* {
        void* p = ws + off;
        off = (off + bytes + 255) & ~(size_t)255;
        return p;
    };
    // ~815 KB total: proven-safe footprint.
    bf16x8* predS = (bf16x8*)take((size_t)PAD_SLOTS * 16);
    bf16x8* gtS   = (bf16x8*)take((size_t)PAD_SLOTS * 16);
    unsigned int* minF = (unsigned int*)take((size_t)nP * 4);
    unsigned int* minB = (unsigned int*)take((size_t)nG * 4);
    (void)ws_size; (void)n_in; (void)out_size;

    expandSplit<<<(PAD_SLOTS + 255) / 256, 256, 0, stream>>>(pred, gt, predS, gtS,
                                                             minF, minB, nP, nG);

    const int maxTiles = tilesP > tilesG ? tilesP : tilesG;
    dim3 grid((maxTiles + WAVES - 1) / WAVES, SPLIT, 2);
    chamfer_mfma<<<grid, BLK, 0, stream>>>(predS, gtS, minF, minB, nP, nG);

    chamfer_finalize<<<1, 1024, 0, stream>>>(minF, minB, (float*)d_out, nP, nG);
}

// Round 10
// 40.206 us; speedup vs baseline: 2.2087x; 1.3490x over previous
//
#include <hip/hip_runtime.h>

typedef __bf16 bf16x8 __attribute__((ext_vector_type(8)));
typedef float f32x16 __attribute__((ext_vector_type(16)));

#define BLK      256
#define WPB      4                  // waves per block
#define TPW      2                  // own tiles per wave (1 LDS read feeds 2 MFMAs)
#define TPB      (WPB * TPW)        // 8 own tiles per block
#define CH_TILES 40                 // stream tiles per block: 40 KB LDS
#define CH_SLOTS (CH_TILES * 32)    // 1280 stream points per y-block

__device__ __forceinline__ float min3f(float a, float b, float c) {
    float d;
    asm("v_min3_f32 %0, %1, %2, %3" : "=v"(d) : "v"(a), "v"(b), "v"(c));
    return d;
}
// MFMA with early-clobber destination: D != {A,B,C}; zero-C stays pinned.
__device__ __forceinline__ f32x16 mfma_tile(bf16x8 a, bf16x8 b, f32x16 zc) {
    f32x16 d;
    asm("v_mfma_f32_32x32x16_bf16 %0, %1, %2, %3"
        : "=&v"(d) : "v"(a), "v"(b), "v"(zc));
    return d;
}
// Order-preserving float -> uint key: min over keys == min over floats.
__device__ __forceinline__ unsigned int f2key(float f) {
    unsigned int b = __float_as_uint(f);
    return (b & 0x80000000u) ? ~b : (b | 0x80000000u);
}
__device__ __forceinline__ float key2f(unsigned int k) {
    unsigned int b = (k & 0x80000000u) ? (k ^ 0x80000000u) : ~k;
    return __uint_as_float(b);
}
// hi/lo bf16 split of a point + its |s|^2.
__device__ __forceinline__ void splitp(float x, float y, float z,
    __bf16& xh, __bf16& xl, __bf16& yh, __bf16& yl,
    __bf16& zh, __bf16& zl, __bf16& s2h, __bf16& s2l)
{
    float s2 = fmaf(x, x, fmaf(y, y, z*z));
    xh = (__bf16)x;  xl = (__bf16)(x - (float)xh);
    yh = (__bf16)y;  yl = (__bf16)(y - (float)yh);
    zh = (__bf16)z;  zl = (__bf16)(z - (float)zh);
    s2h = (__bf16)s2; s2l = (__bf16)(s2 - (float)s2h);
}

// d2 = p2 + g2 - 2<p,g> via mfma_f32_32x32x16_bf16, split-bf16 K recipe
// (A=stream | B=own):  k0:1|p2h k1:1|p2l k2:g2h|1 k3:g2l|1
//   x: k4:gxh|-2pxh k5:gxl|-2pxh k6:gxh|-2pxl  (y: k7-9, z: k10-12; 13-15: 0)
// exact to ~2^-17 (absmax 1.2e-4 verified). Each wave owns TWO 32-point own
// tiles (bf0,bf1): one ds_read_b128 A-frag feeds 2 MFMAs (halves LDS BW to
// ~64 B/cyc/CU < 85 measured ceiling). Rotation by NAMING (d00..d11): a D
// tuple is folded 4 MFMAs (~128cyc) after its issue, then its name is
// reassigned -- no register copies. Split transform fused into LDS staging
// from raw inputs; min-keys pre-set to 0xFF by memsetAsync.
__global__ __launch_bounds__(BLK, 4) void chamfer_mfma(
    const float* __restrict__ pred, const float* __restrict__ gt,
    unsigned int* __restrict__ minsAll, int nP, int nG)
{
    __shared__ bf16x8 sh[CH_TILES * 64];

    const int dir  = blockIdx.z;            // 0: own pred / stream gt
    const int nOwn = dir ? nG : nP;
    const int nStr = dir ? nP : nG;
    const int ownTiles = (nOwn + 31) >> 5;
    unsigned int* mins = minsAll + (dir ? nP : 0);

    const int tid = threadIdx.x, wave = tid >> 6, lane = tid & 63, col = lane & 31;
    const __bf16 one = (__bf16)1.0f, zero = (__bf16)0.0f, big = (__bf16)1.0e30f;

    // ---- stage CH_TILES stream tiles into LDS in A-layout, from raw input ----
    #pragma unroll
    for (int j = tid; j < CH_SLOTS; j += BLK) {
        const int g = blockIdx.y * CH_SLOTS + j;
        float x = 0.f, y = 0.f, z = 0.f;
        const bool v = g < nStr;
        if (v) {
            if (dir == 0) { float4 G = ((const float4*)gt)[g]; x = G.x; y = G.y; z = G.z; }
            else          { x = pred[3*g]; y = pred[3*g+1]; z = pred[3*g+2]; }
        }
        __bf16 xh, xl, yh, yl, zh, zl, s2h, s2l;
        splitp(x, y, z, xh, xl, yh, yl, zh, zl, s2h, s2l);
        if (!v) { s2h = big; s2l = big; }     // pad: d2 ~ 2e30, never wins
        const int t = j >> 5, q = j & 31;
        sh[t*64 + q]      = bf16x8{one, one, s2h, s2l, xh, xl, xh, yh};
        sh[t*64 + 32 + q] = bf16x8{yl, yh, zh, zl, zh, zero, zero, zero};
    }

    // ---- B fragments for the wave's two own tiles (from raw input) ----
    const int tileA = blockIdx.x * TPB + wave * TPW;
    const int tileB = tileA + 1;
    bf16x8 bf0, bf1;
    {
        auto mk = [&](int tile) -> bf16x8 {
            int i = tile * 32 + col; i = min(i, nOwn - 1);   // clamp: dummy work
            float x, y, z;
            if (dir == 0) { x = pred[3*i]; y = pred[3*i+1]; z = pred[3*i+2]; }
            else          { float4 G = ((const float4*)gt)[i]; x = G.x; y = G.y; z = G.z; }
            __bf16 xh, xl, yh, yl, zh, zl, q2h, q2l;
            splitp(x, y, z, xh, xl, yh, yl, zh, zl, q2h, q2l);
            const __bf16 m2xh = (__bf16)(-2.f*(float)xh), m2xl = (__bf16)(-2.f*(float)xl);
            const __bf16 m2yh = (__bf16)(-2.f*(float)yh), m2yl = (__bf16)(-2.f*(float)yl);
            const __bf16 m2zh = (__bf16)(-2.f*(float)zh), m2zl = (__bf16)(-2.f*(float)zl);
            return (lane < 32)
                ? bf16x8{q2h, q2l, one, one, m2xh, m2xh, m2xl, m2yh}
                : bf16x8{m2yh, m2yl, m2zh, m2zh, m2zl, zero, zero, zero};
        };
        bf0 = mk(tileA);
        bf1 = mk(tileB);
    }
    __syncthreads();

    float rm0[8], rm1[8];
    #pragma unroll
    for (int j = 0; j < 8; ++j) { rm0[j] = 3.0e38f; rm1[j] = 3.0e38f; }
    f32x16 zc = {};   // pinned zero-C

#define FOLD(rm, dv) { \
    rm[0] = min3f(dv[0],  dv[1],  rm[0]);  rm[1] = min3f(dv[2],  dv[3],  rm[1]); \
    rm[2] = min3f(dv[4],  dv[5],  rm[2]);  rm[3] = min3f(dv[6],  dv[7],  rm[3]); \
    rm[4] = min3f(dv[8],  dv[9],  rm[4]);  rm[5] = min3f(dv[10], dv[11], rm[5]); \
    rm[6] = min3f(dv[12], dv[13], rm[6]);  rm[7] = min3f(dv[14], dv[15], rm[7]); }

    // prologue: 2 stream tiles in flight (4 MFMAs)
    bf16x8 aA = sh[lane];
    f32x16 d00 = mfma_tile(aA, bf0, zc);
    f32x16 d01 = mfma_tile(aA, bf1, zc);
    bf16x8 aB = sh[64 + lane];
    f32x16 d10 = mfma_tile(aB, bf0, zc);
    f32x16 d11 = mfma_tile(aB, bf1, zc);

    #pragma unroll
    for (int t = 2; t < CH_TILES; t += 2) {
        bf16x8 a0 = sh[t*64 + lane];
        FOLD(rm0, d00); FOLD(rm1, d01);          // fold tiles issued 4 MFMAs ago
        d00 = mfma_tile(a0, bf0, zc);
        d01 = mfma_tile(a0, bf1, zc);
        bf16x8 a1 = sh[(t+1)*64 + lane];
        FOLD(rm0, d10); FOLD(rm1, d11);
        d10 = mfma_tile(a1, bf0, zc);
        d11 = mfma_tile(a1, bf1, zc);
    }
    FOLD(rm0, d00); FOLD(rm1, d01);
    FOLD(rm0, d10); FOLD(rm1, d11);
#undef FOLD

    float mA, mB;
    { float a = min3f(rm0[0], rm0[1], rm0[2]);
      float b = min3f(rm0[3], rm0[4], rm0[5]);
      float c = min3f(rm0[6], rm0[7], a);
      mA = fminf(fminf(b, c), 3.0e38f); }        // also NaN-sanitizes
    { float a = min3f(rm1[0], rm1[1], rm1[2]);
      float b = min3f(rm1[3], rm1[4], rm1[5]);
      float c = min3f(rm1[6], rm1[7], a);
      mB = fminf(fminf(b, c), 3.0e38f); }

    const int idxA = tileA * 32 + col;
    const int idxB = tileB * 32 + col;
    if (tileA < ownTiles && idxA < nOwn) atomicMin(&mins[idxA], f2key(mA));
    if (tileB < ownTiles && idxB < nOwn) atomicMin(&mins[idxB], f2key(mB));
}

// Stage 1: per-block partial sums (scaled). Untouched keys decode to 1e30 so
// a non-running min kernel shows as a HUGE error, not a silent 0.
__global__ __launch_bounds__(BLK) void chamfer_reduce1(
    const unsigned int* __restrict__ mins, float* __restrict__ part,
    int nP, int nG, float invP, float invG)
{
    const int i = blockIdx.x * BLK + threadIdx.x;
    float v = 0.f;
    if (i < nP + nG) {
        const unsigned int k = mins[i];
        const float d = (k == 0xFFFFFFFFu) ? 1.0e30f : fmaxf(0.f, key2f(k));
        v = d * (i < nP ? invP : invG);
    }
    #pragma unroll
    for (int o = 32; o > 0; o >>= 1) v += __shfl_xor(v, o);
    __shared__ float r[WPB];
    const int wid = threadIdx.x >> 6, lane = threadIdx.x & 63;
    if (lane == 0) r[wid] = v;
    __syncthreads();
    if (threadIdx.x == 0) part[blockIdx.x] = r[0] + r[1] + r[2] + r[3];
}

// Stage 2: one block, fixed-order deterministic sum of the partials.
__global__ __launch_bounds__(BLK) void chamfer_reduce2(
    const float* __restrict__ part, float* __restrict__ out, int nPart)
{
    float v = 0.f;
    for (int i = threadIdx.x; i < nPart; i += BLK) v += part[i];
    #pragma unroll
    for (int o = 32; o > 0; o >>= 1) v += __shfl_xor(v, o);
    __shared__ float r[WPB];
    const int wid = threadIdx.x >> 6, lane = threadIdx.x & 63;
    if (lane == 0) r[wid] = v;
    __syncthreads();
    if (threadIdx.x == 0) out[0] = r[0] + r[1] + r[2] + r[3];
}

extern "C" void kernel_launch(void* const* d_in, const int* in_sizes, int n_in,
                              void* d_out, int out_size, void* d_ws, size_t ws_size,
                              hipStream_t stream)
{
    const float* pred = (const float*)d_in[0];
    const float* gt   = (const float*)d_in[1];
    const int nP = in_sizes[0] / 3;
    const int nG = in_sizes[1] / 4;
    const int nTot = nP + nG;

    unsigned int* mins = (unsigned int*)d_ws;                       // nTot keys
    const int nPart = (nTot + BLK - 1) / BLK;                       // 157
    float* part = (float*)((char*)d_ws + (((size_t)nTot * 4 + 255) & ~(size_t)255));
    (void)ws_size; (void)n_in; (void)out_size;

    hipMemsetAsync(mins, 0xFF, (size_t)nTot * 4, stream);           // keys = +inf

    const int maxN = nP > nG ? nP : nG;
    const int tilesMax = (maxN + 31) / 32;                          // 625
    dim3 grid((tilesMax + TPB - 1) / TPB,                           // 79
              (maxN + CH_SLOTS - 1) / CH_SLOTS,                     // 16
              2);
    chamfer_mfma<<<grid, BLK, 0, stream>>>(pred, gt, mins, nP, nG);

    chamfer_reduce1<<<nPart, BLK, 0, stream>>>(mins, part, nP, nG,
                                               1.0f / (float)nP, 1.0f / (float)nG);
    chamfer_reduce2<<<1, BLK, 0, stream>>>(part, (float*)d_out, nPart);
}